// Round 9
// baseline (692.291 us; speedup 1.0000x reference)
//
#include <hip/hip_runtime.h>
#include <hip/hip_bf16.h>

typedef __bf16 bf16;
typedef __bf16 bf16x8 __attribute__((ext_vector_type(8)));
typedef __bf16 bf16x4 __attribute__((ext_vector_type(4)));
typedef float  f32x4  __attribute__((ext_vector_type(4)));

#define NB 8
#define NS 1024
#define ND 1024
#define NH 16
#define NDK 64
#define NDFF 4096

static __device__ __forceinline__ f32x4 mfma16(bf16x8 a, bf16x8 b, f32x4 c) {
    return __builtin_amdgcn_mfma_f32_16x16x32_bf16(a, b, c, 0, 0, 0);
}

#define GLDS(g, l) __builtin_amdgcn_global_load_lds( \
    (const __attribute__((address_space(1))) void*)(g), \
    (__attribute__((address_space(3))) void*)(l), 16, 0, 0)

// ---------------------------------------------------------------------------
// prep_all: independent prep tasks in ONE launch. Branch is block-uniform.
//   [0,8192)      cvt_x: fp32 x -> bf16 xb
//   [8192,11264)  weight transpose -> bf16 BT layouts (0.125 folded into Wq)
//   [11264,11276) qkv bias pack
//   [11276,11284) mask scan (stable partition of key axis)
//   [11284,11292) zero cvec accumulator + the two grid-sync counters
// ---------------------------------------------------------------------------
__global__ __launch_bounds__(256) void prep_all(
    const float* __restrict__ x, const int* __restrict__ mask,
    const float* __restrict__ Wq, const float* __restrict__ Wk, const float* __restrict__ Wv,
    const float* __restrict__ Wo, const float* __restrict__ W1, const float* __restrict__ W2,
    const float* __restrict__ bq, const float* __restrict__ bk, const float* __restrict__ bv,
    bf16* __restrict__ xb, bf16* __restrict__ wqkvT, bf16* __restrict__ WoT,
    bf16* __restrict__ W1T, bf16* __restrict__ W2T, float* __restrict__ bqkv,
    int* __restrict__ newpos, int* __restrict__ Ucnt, float* __restrict__ cvec,
    int* __restrict__ ctrs)
{
    __shared__ __align__(16) char shraw[64 * 65 * 4];
    int bid = blockIdx.x, t = threadIdx.x;
    if (bid < 8192) {
        int idx = bid * 256 + t;
        float4 v = ((const float4*)x)[idx];
        bf16x4 o = { (bf16)v.x, (bf16)v.y, (bf16)v.z, (bf16)v.w };
        ((bf16x4*)xb)[idx] = o;
    } else if (bid < 11264) {
        float (*T)[65] = (float (*)[65])shraw;
        int tb = bid - 8192;
        const float* src; bf16* dst; int srcLd, dstLd, tR, tC; bool scale = false;
        if (tb < 768) {                        // Wq/Wk/Wv per-head [1024x64] -> [64x1024]
            int mat = tb >> 4, ty = tb & 15;
            int h = mat & 15, type = mat >> 4;
            const float* W = (type == 0) ? Wq : (type == 1 ? Wk : Wv);
            src = W + (size_t)h * ND * NDK;
            srcLd = NDK; tR = ty * 64; tC = 0;
            dst = wqkvT + ((size_t)type * 1024 + h * 64) * ND;
            dstLd = ND;
            scale = (type == 0);
        } else if (tb < 1024) {                // Wo
            int b2 = tb - 768; int ty = b2 >> 4, tx = b2 & 15;
            src = Wo; srcLd = ND; tR = ty * 64; tC = tx * 64; dst = WoT; dstLd = ND;
        } else if (tb < 2048) {                // W1 [1024x4096] -> W1T
            int b2 = tb - 1024; int ty = b2 >> 6, tx = b2 & 63;
            src = W1; srcLd = NDFF; tR = ty * 64; tC = tx * 64; dst = W1T; dstLd = ND;
        } else {                               // W2 [4096x1024] -> W2T
            int b2 = tb - 2048; int ty = b2 >> 4, tx = b2 & 15;
            src = W2; srcLd = ND; tR = ty * 64; tC = tx * 64; dst = W2T; dstLd = NDFF;
        }
        int c0 = t & 63, r0 = t >> 6;
        #pragma unroll
        for (int rr = 0; rr < 16; rr++) {
            int row = rr * 4 + r0;
            T[row][c0] = src[(size_t)(tR + row) * srcLd + tC + c0];
        }
        __syncthreads();
        #pragma unroll
        for (int cc = 0; cc < 16; cc++) {
            int col = cc * 4 + r0;
            float v = T[c0][col];
            if (scale) v *= 0.125f;
            dst[(size_t)(tC + col) * dstLd + tR + c0] = (bf16)v;
        }
    } else if (bid < 11276) {
        int n = (bid - 11264) * 256 + t;
        if (n < 3072) {
            int type = n >> 10, hk = n & 1023;
            const float* bb = (type == 0) ? bq : (type == 1 ? bk : bv);
            float v = bb[hk];
            if (type == 0) v *= 0.125f;
            bqkv[n] = v;
        }
    } else if (bid < 11284) {
        int* sums  = (int*)shraw;
        int* scans = (int*)(shraw + 1024);
        int b = bid - 11276;
        const int* mb = mask + b * NS;
        int m[4], s = 0;
        #pragma unroll
        for (int k = 0; k < 4; k++) { m[k] = (mb[t * 4 + k] != 0) ? 1 : 0; s += m[k]; }
        sums[t] = s;
        __syncthreads();
        if (t == 0) {
            int acc = 0;
            for (int i = 0; i < 256; i++) { scans[i] = acc; acc += sums[i]; }
            scans[256] = acc;
            Ucnt[b] = acc;
        }
        __syncthreads();
        int U = scans[256];
        int p = scans[t];
        #pragma unroll
        for (int k = 0; k < 4; k++) {
            int j = t * 4 + k;
            newpos[b * NS + j] = m[k] ? p : U + (j - p);
            p += m[k];
        }
    } else {
        float4 z = {0.f, 0.f, 0.f, 0.f};
        ((float4*)cvec)[(bid - 11284) * 256 + t] = z;
        if (bid == 11284 && t < 2) ctrs[t] = 0;
    }
}

// ---------------------------------------------------------------------------
// Core B (measured 892 TF on g6): 128x256, BK=64, 8 waves, 2 phases x 16
// MFMA, TRIPLE-buf LDS (144 KiB -> exactly 1 block/CU): stage tile t+2 during
// tile t, counted vmcnt(6) (never 0 in steady state).
// ---------------------------------------------------------------------------
__device__ __forceinline__ void gemmB_core(
    const bf16* __restrict__ A, const bf16* __restrict__ BT, int K,
    int rowBase, int colBase, f32x4 (&acc)[4][4], bf16* As, bf16* Bs)
{
    constexpr int ABUF = 128 * 64, BBUF = 256 * 64;
    const int tid = threadIdx.x, lane = tid & 63, wid = tid >> 6;
    const int wm = wid >> 2, wn = wid & 3;
    const int lrow = lane & 15, lq = lane >> 4;
    const int srow = lane >> 3, gblk = (lane & 7) ^ srow;
    const int co0 = (lq ^ (lrow & 7)) * 8;
    const int co1 = ((4 + lq) ^ (lrow & 7)) * 8;
    f32x4 zz = {0.f, 0.f, 0.f, 0.f};
    #pragma unroll
    for (int i = 0; i < 4; i++)
        #pragma unroll
        for (int j = 0; j < 4; j++) acc[i][j] = zz;
    const bf16* Ag = A  + (size_t)(rowBase + wid * 8 + srow) * K + gblk * 8;
    const bf16* Bg = BT + (size_t)(colBase + wid * 8 + srow) * K + gblk * 8;

#define SGA2(kt, bi, rr) GLDS(Ag + (size_t)(kt) * 64 + (size_t)(rr) * 64 * K, \
                              As + (bi) * ABUF + ((rr) * 64 + wid * 8) * 64)
#define SGB2(kt, bi, rr) GLDS(Bg + (size_t)(kt) * 64 + (size_t)(rr) * 64 * K, \
                              Bs + (bi) * BBUF + ((rr) * 64 + wid * 8) * 64)
#define RDA2() do { _Pragma("unroll") for (int i_ = 0; i_ < 4; i_++) { \
    int ro_ = (wm * 64 + i_ * 16 + lrow) * 64; \
    af[i_][0] = *(const bf16x8*)&Ab[ro_ + co0]; \
    af[i_][1] = *(const bf16x8*)&Ab[ro_ + co1]; } } while (0)
#define RDB2(dst, NS_) do { _Pragma("unroll") for (int j_ = 0; j_ < 2; j_++) { \
    int ro_ = (wn * 64 + (NS_) * 32 + j_ * 16 + lrow) * 64; \
    dst[j_][0] = *(const bf16x8*)&Bb[ro_ + co0]; \
    dst[j_][1] = *(const bf16x8*)&Bb[ro_ + co1]; } } while (0)
#define CLUSTER_B(bfx, JO) do { \
    __builtin_amdgcn_s_barrier(); \
    asm volatile("s_waitcnt lgkmcnt(0)" ::: "memory"); \
    __builtin_amdgcn_sched_barrier(0); \
    __builtin_amdgcn_s_setprio(1); \
    _Pragma("unroll") \
    for (int i_ = 0; i_ < 4; i_++) \
        _Pragma("unroll") \
        for (int j_ = 0; j_ < 2; j_++) { \
            acc[i_][(JO) + j_] = mfma16(af[i_][0], bfx[j_][0], acc[i_][(JO) + j_]); \
            acc[i_][(JO) + j_] = mfma16(af[i_][1], bfx[j_][1], acc[i_][(JO) + j_]); \
        } \
    __builtin_amdgcn_s_setprio(0); \
} while (0)

    const int nt = K >> 6;
    SGA2(0, 0, 0); SGA2(0, 0, 1);
    SGB2(0, 0, 0); SGB2(0, 0, 1); SGB2(0, 0, 2); SGB2(0, 0, 3);
    SGA2(1, 1, 0); SGA2(1, 1, 1);
    SGB2(1, 1, 0); SGB2(1, 1, 1); SGB2(1, 1, 2); SGB2(1, 1, 3);
    asm volatile("s_waitcnt vmcnt(6)" ::: "memory");
    __builtin_amdgcn_s_barrier();

    int ci = 0, si = 2;
    for (int t = 0; t < nt; ++t) {
        const bf16* Ab = As + ci * ABUF;
        const bf16* Bb = Bs + ci * BBUF;
        const bool pf = (t + 2 < nt);
        bf16x8 af[4][2], bf0[2][2], bf1[2][2];
        RDA2(); RDB2(bf0, 0);
        if (pf) { SGA2(t + 2, si, 0); SGA2(t + 2, si, 1); SGB2(t + 2, si, 0); SGB2(t + 2, si, 1); }
        CLUSTER_B(bf0, 0);
        __builtin_amdgcn_s_barrier();
        RDB2(bf1, 1);
        if (pf) { SGB2(t + 2, si, 2); SGB2(t + 2, si, 3); }
        CLUSTER_B(bf1, 2);
        if (pf)                asm volatile("s_waitcnt vmcnt(6)" ::: "memory");
        else if (t + 1 < nt)   asm volatile("s_waitcnt vmcnt(0)" ::: "memory");
        __builtin_amdgcn_s_barrier();
        ci = (ci == 2) ? 0 : ci + 1;
        si = (si == 2) ? 0 : si + 1;
    }
#undef SGA2
#undef SGB2
#undef RDA2
#undef RDB2
#undef CLUSTER_B
}

// ---------------------------------------------------------------------------
// 8-phase 256x256 core (measured best for g5).
// ---------------------------------------------------------------------------
__device__ __forceinline__ void gemm8p(
    const bf16* __restrict__ A, const bf16* __restrict__ BT, int K,
    int rowBase, int colBase, f32x4 (&acc)[8][4], bf16* As, bf16* Bs)
{
    constexpr int SETSZ = 256 * 64;
    const int tid = threadIdx.x, lane = tid & 63, wid = tid >> 6;
    const int wm = wid >> 2, wn = wid & 3;
    const int lrow = lane & 15, lq = lane >> 4;
    const int s8 = lane >> 3, gblk = (lane & 7) ^ s8;
    const int co0 = (lq ^ (lrow & 7)) * 8;
    const int co1 = ((4 + lq) ^ (lrow & 7)) * 8;
    f32x4 zz = {0.f, 0.f, 0.f, 0.f};
    #pragma unroll
    for (int i = 0; i < 8; i++)
        #pragma unroll
        for (int j = 0; j < 4; j++) acc[i][j] = zz;
    const bf16* Ag = A  + (size_t)(rowBase + wid * 8 + s8) * K + gblk * 8;
    const bf16* Bg = BT + (size_t)(colBase + wid * 8 + s8) * K + gblk * 8;

#define SG_A(kt, set, h) do { \
    GLDS(Ag + (size_t)((h) * 128) * K + (kt) * 64, \
         As + (set) * SETSZ + ((h) * 128 + wid * 8) * 64); \
    GLDS(Ag + (size_t)((h) * 128 + 64) * K + (kt) * 64, \
         As + (set) * SETSZ + ((h) * 128 + 64 + wid * 8) * 64); \
} while (0)
#define SG_B(kt, set, h) do { \
    GLDS(Bg + (size_t)((h) * 128) * K + (kt) * 64, \
         Bs + (set) * SETSZ + ((h) * 128 + wid * 8) * 64); \
    GLDS(Bg + (size_t)((h) * 128 + 64) * K + (kt) * 64, \
         Bs + (set) * SETSZ + ((h) * 128 + 64 + wid * 8) * 64); \
} while (0)
#define RD_A(dst, base, ms) do { _Pragma("unroll") for (int i_ = 0; i_ < 4; i_++) { \
    int ro_ = (wm * 128 + (ms) * 64 + i_ * 16 + lrow) * 64; \
    dst[i_][0] = *(const bf16x8*)&(base)[ro_ + co0]; \
    dst[i_][1] = *(const bf16x8*)&(base)[ro_ + co1]; } } while (0)
#define RD_B(dst, base, ns) do { _Pragma("unroll") for (int j_ = 0; j_ < 2; j_++) { \
    int ro_ = (wn * 64 + (ns) * 32 + j_ * 16 + lrow) * 64; \
    dst[j_][0] = *(const bf16x8*)&(base)[ro_ + co0]; \
    dst[j_][1] = *(const bf16x8*)&(base)[ro_ + co1]; } } while (0)
#define CL8(av, bv, ms, ns) do { \
    __builtin_amdgcn_s_setprio(1); \
    _Pragma("unroll") for (int i_ = 0; i_ < 4; i_++) \
    _Pragma("unroll") for (int j_ = 0; j_ < 2; j_++) { \
        acc[(ms) * 4 + i_][(ns) * 2 + j_] = \
            mfma16(av[i_][0], bv[j_][0], acc[(ms) * 4 + i_][(ns) * 2 + j_]); \
        acc[(ms) * 4 + i_][(ns) * 2 + j_] = \
            mfma16(av[i_][1], bv[j_][1], acc[(ms) * 4 + i_][(ns) * 2 + j_]); } \
    __builtin_amdgcn_s_setprio(0); \
} while (0)
#define BAR8 __builtin_amdgcn_s_barrier()
#define VM4 asm volatile("s_waitcnt vmcnt(4)" ::: "memory")
#define VM0 asm volatile("s_waitcnt vmcnt(0)" ::: "memory")

    const int nt = K >> 6, nIter = nt >> 1;
    SG_B(0, 0, 0); SG_B(0, 0, 1);
    SG_A(0, 0, 0); SG_A(0, 0, 1);
    SG_B(1, 1, 0); SG_B(1, 1, 1);
    VM4; BAR8;
    const bf16* A0b = As;           const bf16* B0b = Bs;
    const bf16* A1b = As + SETSZ;   const bf16* B1b = Bs + SETSZ;
    for (int J = 0; J < nIter; ++J) {
        const int v = 2 * J + 1;
        const bool pf = (J + 1 < nIter);
        bf16x8 a0[4][2], a1[4][2], b0[2][2], b1[2][2];
        RD_A(a0, A0b, 0); RD_B(b0, B0b, 0);
        SG_A(v, 1, 0);
        BAR8; CL8(a0, b0, 0, 0); BAR8;
        RD_B(b1, B0b, 1);
        SG_A(v, 1, 1);
        BAR8; CL8(a0, b1, 0, 1); BAR8;
        RD_A(a1, A0b, 1);
        if (pf) SG_B(v + 1, 0, 0);
        BAR8; CL8(a1, b1, 1, 1); BAR8;
        if (pf) SG_B(v + 1, 0, 1);
        BAR8; CL8(a1, b0, 1, 0);
        if (pf) { VM4; } else { VM0; }
        BAR8;
        RD_A(a0, A1b, 0); RD_B(b0, B1b, 0);
        if (pf) SG_A(v + 1, 0, 0);
        BAR8; CL8(a0, b0, 0, 0); BAR8;
        RD_B(b1, B1b, 1);
        if (pf) SG_A(v + 1, 0, 1);
        BAR8; CL8(a0, b1, 0, 1); BAR8;
        RD_A(a1, A1b, 1);
        if (pf) SG_B(v + 2, 1, 0);
        BAR8; CL8(a1, b1, 1, 1); BAR8;
        if (pf) SG_B(v + 2, 1, 1);
        BAR8; CL8(a1, b0, 1, 0);
        if (pf) { VM4; } else { VM0; }
        BAR8;
    }
#undef SG_A
#undef SG_B
#undef RD_A
#undef RD_B
#undef CL8
#undef BAR8
#undef VM4
#undef VM0
}

// ---------------------------------------------------------------------------
// Grid-wide rendezvous for grid<=256 blocks at 1 block/CU (co-residency
// guaranteed by the 144KiB LDS footprint). Counter zeroed by prep_all each
// graph replay. __threadfence = device-scope fence (G16).
// ---------------------------------------------------------------------------
__device__ __forceinline__ void grid_rendezvous(int* ctr, int nblocks)
{
    __threadfence();
    __syncthreads();
    if (threadIdx.x == 0) {
        atomicAdd(ctr, 1);
        while (atomicAdd(ctr, 0) < nblocks) __builtin_amdgcn_s_sleep(8);
    }
    __syncthreads();
    __threadfence();
}

// Per-wave row LayerNorm: wave handles one full row (64 lanes x 16 elems),
// shuffle-only reduction (no LDS, no barriers).
template<bool WRITE_F32>
__device__ __forceinline__ void ln_rows(
    const bf16* __restrict__ in, bf16* __restrict__ outb, float* __restrict__ outf,
    const float* gv, const float* bv, int rowBase)
{
    const int lane = threadIdx.x & 63, wid = threadIdx.x >> 6;
    #pragma unroll
    for (int it = 0; it < 4; it++) {
        int row = rowBase + it * 8 + wid;
        const bf16* p = in + (size_t)row * ND + lane * 16;
        bf16x8 v0 = *(const bf16x8*)p;
        bf16x8 v1 = *(const bf16x8*)(p + 8);
        float vv[16];
        float s = 0.f, q = 0.f;
        #pragma unroll
        for (int k = 0; k < 8; k++) { vv[k] = (float)v0[k]; vv[8 + k] = (float)v1[k]; }
        #pragma unroll
        for (int k = 0; k < 16; k++) { s += vv[k]; q += vv[k] * vv[k]; }
        #pragma unroll
        for (int m = 1; m < 64; m <<= 1) { s += __shfl_xor(s, m); q += __shfl_xor(q, m); }
        float mean = s * (1.f / 1024.f);
        float var = q * (1.f / 1024.f) - mean * mean;
        float rstd = 1.f / sqrtf(var + 1e-5f);
        if (WRITE_F32) {
            float4 o[4];
            #pragma unroll
            for (int k = 0; k < 16; k++)
                ((float*)o)[k] = (vv[k] - mean) * rstd * gv[k] + bv[k];
            float* dst = outf + (size_t)row * ND + lane * 16;
            #pragma unroll
            for (int k = 0; k < 4; k++) ((float4*)dst)[k] = o[k];
        } else {
            bf16x8 o0, o1;
            #pragma unroll
            for (int k = 0; k < 8; k++) {
                o0[k] = (bf16)((vv[k] - mean) * rstd * gv[k] + bv[k]);
                o1[k] = (bf16)((vv[8 + k] - mean) * rstd * gv[8 + k] + bv[8 + k]);
            }
            bf16* dst = outb + (size_t)row * ND + lane * 16;
            *(bf16x8*)dst = o0;
            *(bf16x8*)(dst + 8) = o1;
        }
    }
}

// G1: xb @ [Wq|Wk|Wv] + bias; Q row-major, K/V rows through newpos (compacted).
// Core B (128x256), grid 768 (64 bm x 12 bn), XCD-swizzled.
__global__ __launch_bounds__(512, 2) void g1_qkv(
    const bf16* __restrict__ x, const bf16* __restrict__ wqkvT, const float* __restrict__ bqkv,
    const int* __restrict__ newpos,
    bf16* __restrict__ Q, bf16* __restrict__ Kb, bf16* __restrict__ Vb)
{
    __shared__ bf16 As[3 * 128 * 64], Bs[3 * 256 * 64];   // 144 KiB
    f32x4 acc[4][4];
    int g = blockIdx.x;
    int sw = (g & 7) * 96 + (g >> 3);
    int bm = sw / 12, bn = sw % 12;
    int rowBase = bm * 128, colBase = bn * 256;
    gemmB_core(x, wqkvT, ND, rowBase, colBase, acc, As, Bs);
    const int tid = threadIdx.x, lane = tid & 63, wid = tid >> 6;
    const int wm = wid >> 2, wn = wid & 3, lrow = lane & 15, lq = lane >> 4;
    const int type = colBase >> 10;
    int spv[4][4];
    if (type != 0) {
        #pragma unroll
        for (int i = 0; i < 4; i++)
            #pragma unroll
            for (int r = 0; r < 4; r++) {
                int grow = rowBase + wm * 64 + i * 16 + lq * 4 + r;
                spv[i][r] = newpos[grow];
            }
    }
    #pragma unroll
    for (int j = 0; j < 4; j++) {
        int gcol = colBase + wn * 64 + j * 16 + lrow;
        float bias = bqkv[gcol];
        int h = (gcol >> 6) & 15, kk = gcol & 63;
        bf16* dst = (type == 0) ? Q : (type == 1 ? Kb : Vb);
        #pragma unroll
        for (int i = 0; i < 4; i++) {
            #pragma unroll
            for (int r = 0; r < 4; r++) {
                int grow = rowBase + wm * 64 + i * 16 + lq * 4 + r;
                int b = grow >> 10;
                int s = (type == 0) ? (grow & 1023) : spv[i][r];
                dst[((size_t)(b * NH + h) * NS + s) * NDK + kk] = (bf16)(acc[i][j][r] + bias);
            }
        }
    }
}

// G2V: merged g2_stats (blockIdx.x < 8) + vt_trans-with-cvec (x in [8,24)).
// Both depend only on g1's outputs; block-uniform branch; LDS aliased.
__global__ __launch_bounds__(256) void g2v(
    const bf16* __restrict__ Q, const bf16* __restrict__ Kb, const bf16* __restrict__ Vb,
    const int* __restrict__ Ucnt, float2* __restrict__ alpha,
    bf16* __restrict__ Vt, float* __restrict__ cvec)
{
    __shared__ __align__(16) char sraw[128 * 64 * 2];   // 16 KB
    int bh = blockIdx.y, b = bh >> 4;
    const int tid = threadIdx.x;
    if (blockIdx.x >= 8) {
        // ---- vt_trans role: Vb [bh][s][kk] -> Vt [bh][kk][s]; masked-tail
        //      column sums accumulated into cvec (raw; g3 scales by 1/1024).
        bf16* T = (bf16*)sraw;                            // 64*72*2 = 9216 B
        float (*red)[64] = (float (*)[64])(sraw + 64 * 72 * 2);
        int s0 = (blockIdx.x - 8) * 64;
        const bf16* src = Vb + ((size_t)bh * NS + s0) * NDK;
        #pragma unroll
        for (int it = 0; it < 2; it++) {
            int g = tid + it * 256;
            int row = g >> 3, c = (g & 7) * 8;
            *(bf16x8*)&T[row * 72 + c] = *(const bf16x8*)&src[row * NDK + c];
        }
        __syncthreads();
        #pragma unroll
        for (int it = 0; it < 2; it++) {
            int g = tid + it * 256;
            int kk = g >> 3, sc = (g & 7) * 8;
            bf16x8 v;
            #pragma unroll
            for (int t = 0; t < 8; t++) v[t] = T[(sc + t) * 72 + kk];
            *(bf16x8*)&Vt[((size_t)bh * NDK + kk) * NS + s0 + sc] = v;
        }
        int U = Ucnt[b];
        int lo = U - s0;
        if (lo < 0) lo = 0;
        if (lo < 64) {                         // block-uniform
            int kk = tid & 63, ss = tid >> 6;
            float a = 0.f;
            for (int r = lo + ss; r < 64; r += 4) a += (float)T[r * 72 + kk];
            red[ss][kk] = a;
            __syncthreads();
            if (ss == 0)
                atomicAdd(&cvec[bh * 64 + kk], red[0][kk] + red[1][kk] + red[2][kk] + red[3][kk]);
        }
        return;
    }
    // ---- g2 role: column-sum coefficients over COMPACTED keys ----
    bf16* Qs = (bf16*)sraw;                               // 128*64*2 = 16 KB
    int jBase = blockIdx.x * 128;
    int U = Ucnt[b];
    if (jBase >= U) {
        if (tid < 128) {
            float2 z; z.x = 0.f; z.y = 0.f;
            alpha[(size_t)bh * NS + jBase + tid] = z;
        }
        return;
    }
    const bf16* Kp = Kb + (size_t)bh * NS * NDK;
    const bf16* Qp = Q + (size_t)bh * NS * NDK;
    const int lane = tid & 63, wid = tid >> 6;
    const int lrow = lane & 15, lq = lane >> 4;
    bf16x8 kf[2][2];
    #pragma unroll
    for (int jt = 0; jt < 2; jt++)
        #pragma unroll
        for (int kh = 0; kh < 2; kh++)
            kf[jt][kh] = *(const bf16x8*)&Kp[(size_t)(jBase + wid * 32 + jt * 16 + lrow) * NDK + kh * 32 + lq * 8];
    const int srow = lane >> 3;
    const int gblk = (lane & 7) ^ srow;
    float Lacc[2][4];
    #pragma unroll
    for (int jt = 0; jt < 2; jt++)
        #pragma unroll
        for (int r = 0; r < 4; r++) Lacc[jt][r] = 0.f;
    f32x4 zz = {0.f, 0.f, 0.f, 0.f};
    for (int i0 = 0; i0 < NS; i0 += 128) {
        __syncthreads();
        #pragma unroll
        for (int it = 0; it < 4; it++)
            GLDS(Qp + (size_t)(i0 + wid * 32 + it * 8 + srow) * NDK + gblk * 8,
                 Qs + (wid * 32 + it * 8) * 64);
        __syncthreads();
        #pragma unroll
        for (int it = 0; it < 8; it++) {
            bf16x8 qb[2];
            #pragma unroll
            for (int kh = 0; kh < 2; kh++)
                qb[kh] = *(const bf16x8*)&Qs[(it * 16 + lrow) * 64 + ((kh * 4 + lq) ^ (lrow & 7)) * 8];
            #pragma unroll
            for (int jt = 0; jt < 2; jt++) {
                f32x4 s = mfma16(kf[jt][0], qb[0], zz);
                s = mfma16(kf[jt][1], qb[1], s);
                #pragma unroll
                for (int r = 0; r < 4; r++) Lacc[jt][r] += __expf(s[r]);
            }
        }
    }
    #pragma unroll
    for (int jt = 0; jt < 2; jt++) {
        #pragma unroll
        for (int r = 0; r < 4; r++) {
            float v = Lacc[jt][r];
            v += __shfl_xor(v, 1); v += __shfl_xor(v, 2);
            v += __shfl_xor(v, 4); v += __shfl_xor(v, 8);
            if (lrow == 0) {
                int j = jBase + wid * 32 + jt * 16 + lq * 4 + r;
                float2 ac;
                ac.x = (j < U) ? 1.f / v : 0.f;
                ac.y = 0.f;
                alpha[(size_t)bh * NS + j] = ac;
            }
        }
    }
}

// G3: ctx[i][kk] = sum_{compacted j < Ur} a_j*exp(s_ij) * v[j][kk] + cvec/1024
__global__ __launch_bounds__(256) void g3_ctx(
    const bf16* __restrict__ Q, const bf16* __restrict__ Kb, const bf16* __restrict__ Vt,
    const float2* __restrict__ alpha, const int* __restrict__ Ucnt,
    const float* __restrict__ cvec, bf16* __restrict__ ctx)
{
    __shared__ bf16 Ks[64 * 64];
    __shared__ bf16 Vs[64 * 64];
    __shared__ bf16 Ps[4 * 64 * 64];
    int bh = blockIdx.y, iBase = blockIdx.x * 256;
    int b = bh >> 4, h = bh & 15;
    int U = Ucnt[b];
    int Ur = (U + 63) & ~63;
    const bf16* Qp = Q + (size_t)bh * NS * NDK;
    const bf16* Kp = Kb + (size_t)bh * NS * NDK;
    const bf16* Vp = Vt + (size_t)bh * NDK * NS;
    const float2* al = alpha + (size_t)bh * NS;
    const int tid = threadIdx.x, lane = tid & 63, wid = tid >> 6;
    const int lrow = lane & 15, lq = lane >> 4;
    const int iw = iBase + wid * 64;
    bf16x8 qf[4][2];
    #pragma unroll
    for (int it = 0; it < 4; it++)
        #pragma unroll
        for (int kh = 0; kh < 2; kh++)
            qf[it][kh] = *(const bf16x8*)&Qp[(size_t)(iw + it * 16 + lrow) * NDK + kh * 32 + lq * 8];
    const int srow = lane >> 3;
    const int gblk = (lane & 7) ^ srow;
    f32x4 cacc[4][4];
    f32x4 zz = {0.f, 0.f, 0.f, 0.f};
    #pragma unroll
    for (int it = 0; it < 4; it++)
        #pragma unroll
        for (int kt = 0; kt < 4; kt++) cacc[it][kt] = zz;
    bf16* Pw = Ps + wid * 64 * 64;
    for (int j0 = 0; j0 < Ur; j0 += 64) {
        __syncthreads();
        #pragma unroll
        for (int it = 0; it < 2; it++)
            GLDS(Kp + (size_t)(j0 + wid * 16 + it * 8 + srow) * NDK + gblk * 8,
                 Ks + (wid * 16 + it * 8) * 64);
        #pragma unroll
        for (int it = 0; it < 2; it++)
            GLDS(Vp + (size_t)(wid * 16 + it * 8 + srow) * NS + j0 + gblk * 8,
                 Vs + (wid * 16 + it * 8) * 64);
        __syncthreads();
        bf16x8 kb[4][2];
        #pragma unroll
        for (int jt = 0; jt < 4; jt++)
            #pragma unroll
            for (int kh = 0; kh < 2; kh++)
                kb[jt][kh] = *(const bf16x8*)&Ks[(jt * 16 + lrow) * 64 + ((kh * 4 + lq) ^ (lrow & 7)) * 8];
        #pragma unroll
        for (int jt = 0; jt < 4; jt++) {
            float2 acj[4];
            #pragma unroll
            for (int r = 0; r < 4; r++) acj[r] = al[j0 + jt * 16 + lq * 4 + r];
            #pragma unroll
            for (int it = 0; it < 4; it++) {
                f32x4 s = mfma16(kb[jt][0], qf[it][0], zz);
                s = mfma16(kb[jt][1], qf[it][1], s);
                bf16x4 pv;
                #pragma unroll
                for (int r = 0; r < 4; r++)
                    pv[r] = (bf16)(acj[r].x * __expf(s[r]) + acj[r].y);
                int i = it * 16 + lrow;
                int jb = jt * 2 + (lq >> 1);
                *(bf16x4*)&Pw[i * 64 + ((jb ^ (i & 7)) * 8) + (lq & 1) * 4] = pv;
            }
        }
        bf16x8 vb[4][2];
        #pragma unroll
        for (int kt = 0; kt < 4; kt++)
            #pragma unroll
            for (int kh = 0; kh < 2; kh++)
                vb[kt][kh] = *(const bf16x8*)&Vs[(kt * 16 + lrow) * 64 + ((kh * 4 + lq) ^ (lrow & 7)) * 8];
        #pragma unroll
        for (int it = 0; it < 4; it++) {
            bf16x8 pa[2];
            #pragma unroll
            for (int kh = 0; kh < 2; kh++)
                pa[kh] = *(const bf16x8*)&Pw[(it * 16 + lrow) * 64 + ((kh * 4 + lq) ^ (lrow & 7)) * 8];
            #pragma unroll
            for (int kt = 0; kt < 4; kt++) {
                cacc[it][kt] = mfma16(pa[0], vb[kt][0], cacc[it][kt]);
                cacc[it][kt] = mfma16(pa[1], vb[kt][1], cacc[it][kt]);
            }
        }
    }
    #pragma unroll
    for (int kt = 0; kt < 4; kt++) {
        int col = h * NDK + kt * 16 + lrow;
        float cv = cvec[bh * 64 + kt * 16 + lrow] * (1.f / 1024.f);
        #pragma unroll
        for (int it = 0; it < 4; it++) {
            #pragma unroll
            for (int r = 0; r < 4; r++) {
                int i = iw + it * 16 + lq * 4 + r;
                ctx[(size_t)(b * NS + i) * ND + col] = (bf16)(cacc[it][kt][r] + cv);
            }
        }
    }
}

// G4: t1b = bf16(ctx @ Wo + bo + xb), then grid-rendezvous + fused LN1 -> yb.
// Core B, grid 256 (64 bm x 4 bn) = exactly 1 block/CU.
__global__ __launch_bounds__(512, 2) void g4_proj(
    const bf16* __restrict__ ctx, const bf16* __restrict__ WoT, const float* __restrict__ bo,
    const bf16* __restrict__ xb, bf16* __restrict__ t1b,
    const float* __restrict__ ga, const float* __restrict__ ba,
    bf16* __restrict__ yb, int* __restrict__ ctr)
{
    __shared__ bf16 As[3 * 128 * 64], Bs[3 * 256 * 64];   // 144 KiB
    f32x4 acc[4][4];
    int g = blockIdx.x;
    int sw = (g & 7) * 32 + (g >> 3);
    int bm = sw >> 2, bn = sw & 3;
    int rowBase = bm * 128, colBase = bn * 256;
    gemmB_core(ctx, WoT, ND, rowBase, colBase, acc, As, Bs);
    const int tid = threadIdx.x, lane = tid & 63, wid = tid >> 6;
    const int wm = wid >> 2, wn = wid & 3, lrow = lane & 15, lq = lane >> 4;
    #pragma unroll
    for (int j = 0; j < 4; j++) {
        int gcol = colBase + wn * 64 + j * 16 + lrow;
        float bias = bo[gcol];
        #pragma unroll
        for (int i = 0; i < 4; i++) {
            #pragma unroll
            for (int r = 0; r < 4; r++) {
                int grow = rowBase + wm * 64 + i * 16 + lq * 4 + r;
                float v = acc[i][j][r] + bias + (float)xb[(size_t)grow * ND + gcol];
                t1b[(size_t)grow * ND + gcol] = (bf16)v;
            }
        }
    }
    // LN params hoisted (independent of t1b) to hide under the rendezvous
    float gv[16], bv[16];
    #pragma unroll
    for (int k = 0; k < 16; k++) {
        int col = lane * 16 + k;
        gv[k] = ga[col]; bv[k] = ba[col];
    }
    grid_rendezvous(ctr, 256);
    ln_rows<false>(t1b, yb, nullptr, gv, bv, blockIdx.x * 32);
}

// G5: hb = relu(yb @ W1 + b1)   8-phase core, grid 512 (32x16)
__global__ __launch_bounds__(512, 2) void g5_ffn1(
    const bf16* __restrict__ y, const bf16* __restrict__ W1T, const float* __restrict__ b1,
    bf16* __restrict__ hb)
{
    __shared__ bf16 As[2 * 256 * 64], Bs[2 * 256 * 64];   // 128 KiB
    f32x4 acc[8][4];
    int g = blockIdx.x;
    int sw = (g & 7) * 64 + (g >> 3);
    int bm = sw >> 4, bn = sw & 15;
    int rowBase = bm * 256, colBase = bn * 256;
    gemm8p(y, W1T, ND, rowBase, colBase, acc, As, Bs);
    const int tid = threadIdx.x, lane = tid & 63, wid = tid >> 6;
    const int wm = wid >> 2, wn = wid & 3, lrow = lane & 15, lq = lane >> 4;
    #pragma unroll
    for (int j = 0; j < 4; j++) {
        int gcol = colBase + wn * 64 + j * 16 + lrow;
        float bias = b1[gcol];
        #pragma unroll
        for (int i = 0; i < 8; i++) {
            #pragma unroll
            for (int r = 0; r < 4; r++) {
                int grow = rowBase + wm * 128 + i * 16 + lq * 4 + r;
                float v = fmaxf(acc[i][j][r] + bias, 0.f);
                hb[(size_t)grow * NDFF + gcol] = (bf16)v;
            }
        }
    }
}

// G6: zb = bf16(hb @ W2 + b2 + yb), then grid-rendezvous + fused LN2 -> d_out.
// Core B, grid 256 = exactly 1 block/CU.
__global__ __launch_bounds__(512, 2) void g6_ffn2(
    const bf16* __restrict__ hb, const bf16* __restrict__ W2T, const float* __restrict__ b2,
    const bf16* __restrict__ yb, bf16* __restrict__ zb,
    const float* __restrict__ gf, const float* __restrict__ bfb,
    float* __restrict__ outf, int* __restrict__ ctr)
{
    __shared__ bf16 As[3 * 128 * 64], Bs[3 * 256 * 64];   // 144 KiB
    f32x4 acc[4][4];
    int g = blockIdx.x;
    int sw = (g & 7) * 32 + (g >> 3);
    int bm = sw >> 2, bn = sw & 3;
    int rowBase = bm * 128, colBase = bn * 256;
    gemmB_core(hb, W2T, NDFF, rowBase, colBase, acc, As, Bs);
    const int tid = threadIdx.x, lane = tid & 63, wid = tid >> 6;
    const int wm = wid >> 2, wn = wid & 3, lrow = lane & 15, lq = lane >> 4;
    #pragma unroll
    for (int j = 0; j < 4; j++) {
        int gcol = colBase + wn * 64 + j * 16 + lrow;
        float bias = b2[gcol];
        #pragma unroll
        for (int i = 0; i < 4; i++) {
            #pragma unroll
            for (int r = 0; r < 4; r++) {
                int grow = rowBase + wm * 64 + i * 16 + lq * 4 + r;
                float v = acc[i][j][r] + bias + (float)yb[(size_t)grow * ND + gcol];
                zb[(size_t)grow * ND + gcol] = (bf16)v;
            }
        }
    }
    float gv[16], bv[16];
    #pragma unroll
    for (int k = 0; k < 16; k++) {
        int col = lane * 16 + k;
        gv[k] = gf[col]; bv[k] = bfb[col];
    }
    grid_rendezvous(ctr, 256);
    ln_rows<true>(zb, nullptr, outf, gv, bv, blockIdx.x * 32);
}

// ---------------------------------------------------------------------------
extern "C" void kernel_launch(void* const* d_in, const int* in_sizes, int n_in,
                              void* d_out, int out_size, void* d_ws, size_t ws_size,
                              hipStream_t stream)
{
    const float* x    = (const float*)d_in[0];
    const int*   mask = (const int*)d_in[1];
    const float* Wq   = (const float*)d_in[2];
    const float* bq   = (const float*)d_in[3];
    const float* Wk   = (const float*)d_in[4];
    const float* bk   = (const float*)d_in[5];
    const float* Wv   = (const float*)d_in[6];
    const float* bv   = (const float*)d_in[7];
    const float* Wo   = (const float*)d_in[8];
    const float* bo   = (const float*)d_in[9];
    const float* ga   = (const float*)d_in[10];
    const float* ba   = (const float*)d_in[11];
    const float* W1   = (const float*)d_in[12];
    const float* b1   = (const float*)d_in[13];
    const float* W2   = (const float*)d_in[14];
    const float* b2   = (const float*)d_in[15];
    const float* gf   = (const float*)d_in[16];
    const float* bfb  = (const float*)d_in[17];

    size_t off = 0;
    auto alloc = [&](size_t n) { char* p = (char*)d_ws + off; off += (n + 255) & ~(size_t)255; return (void*)p; };
    bf16*   wqkvT = (bf16*)  alloc((size_t)3072 * 1024 * 2);           // 6 MB
    bf16*   WoT   = (bf16*)  alloc((size_t)1024 * 1024 * 2);           // 2 MB
    bf16*   W1T   = (bf16*)  alloc((size_t)4096 * 1024 * 2);           // 8 MB
    bf16*   W2T   = (bf16*)  alloc((size_t)1024 * 4096 * 2);           // 8 MB
    float*  bqkv  = (float*) alloc(3072 * 4);
    float2* alpha = (float2*)alloc((size_t)NB * NH * NS * 8);          // 1 MB
    int*    newpos= (int*)   alloc((size_t)NB * NS * 4);               // 32 KB
    int*    Ucnt  = (int*)   alloc(NB * 4);
    float*  cvec  = (float*) alloc((size_t)NB * NH * NDK * 4);         // 32 KB
    int*    ctrs  = (int*)   alloc(8);                                  // 2 sync counters
    bf16*   xb    = (bf16*)  alloc((size_t)8192 * 1024 * 2);           // 16 MB
    // 64 MB union: Qb|Kb|Vt|ctx live until g4; hb (g5/g6) aliases the whole block
    bf16*   ub    = (bf16*)  alloc((size_t)8192 * 4096 * 2);           // 64 MB
    bf16*   Qb    = ub;
    bf16*   Kb    = ub + (size_t)8192 * 1024;
    bf16*   Vt    = ub + (size_t)2 * 8192 * 1024;
    bf16*   ctx   = ub + (size_t)3 * 8192 * 1024;
    bf16*   hb    = ub;
    // 16 MB region shared by Vb (g1->g2v), t1b (g4 write+LN read), zb (g6)
    bf16*   t1b   = (bf16*)  alloc((size_t)8192 * 1024 * 2);           // 16 MB
    bf16*   Vb    = t1b;
    bf16*   zb    = t1b;
    bf16*   yb    = (bf16*)  alloc((size_t)8192 * 1024 * 2);           // 16 MB

    // 7 launches (was 10): vt_trans merged into g2; ln1/ln2 fused into g4/g6
    // via 1-block-per-CU grid rendezvous.
    prep_all<<<11292, 256, 0, stream>>>(x, mask, Wq, Wk, Wv, Wo, W1, W2, bq, bk, bv,
                                        xb, wqkvT, WoT, W1T, W2T, bqkv, newpos, Ucnt, cvec, ctrs);
    g1_qkv<<<768, 512, 0, stream>>>(xb, wqkvT, bqkv, newpos, Qb, Kb, Vb);
    g2v<<<dim3(24, 128), 256, 0, stream>>>(Qb, Kb, Vb, Ucnt, alpha, Vt, cvec);
    g3_ctx<<<dim3(4, 128), 256, 0, stream>>>(Qb, Kb, Vt, alpha, Ucnt, cvec, ctx);
    g4_proj<<<256, 512, 0, stream>>>(ctx, WoT, bo, xb, t1b, ga, ba, yb, ctrs);
    g5_ffn1<<<512, 512, 0, stream>>>(yb, W1T, b1, hb);
    g6_ffn2<<<256, 512, 0, stream>>>(hb, W2T, b2, yb, zb, gf, bfb, (float*)d_out, ctrs + 1);
}

// Round 10
// 481.410 us; speedup vs baseline: 1.4380x; 1.4380x over previous
//
#include <hip/hip_runtime.h>
#include <hip/hip_bf16.h>

typedef __bf16 bf16;
typedef __bf16 bf16x8 __attribute__((ext_vector_type(8)));
typedef __bf16 bf16x4 __attribute__((ext_vector_type(4)));
typedef float  f32x4  __attribute__((ext_vector_type(4)));

#define NB 8
#define NS 1024
#define ND 1024
#define NH 16
#define NDK 64
#define NDFF 4096

static __device__ __forceinline__ f32x4 mfma16(bf16x8 a, bf16x8 b, f32x4 c) {
    return __builtin_amdgcn_mfma_f32_16x16x32_bf16(a, b, c, 0, 0, 0);
}

#define GLDS(g, l) __builtin_amdgcn_global_load_lds( \
    (const __attribute__((address_space(1))) void*)(g), \
    (__attribute__((address_space(3))) void*)(l), 16, 0, 0)

// ---------------------------------------------------------------------------
// prep_all: independent prep tasks in ONE launch. Branch is block-uniform.
//   [0,8192)      cvt_x: fp32 x -> bf16 xb
//   [8192,11264)  weight transpose -> bf16 BT layouts (0.125 folded into Wq)
//   [11264,11276) qkv bias pack
//   [11276,11284) mask scan (stable partition of key axis)
//   [11284,11292) zero cvec accumulator
// ---------------------------------------------------------------------------
__global__ __launch_bounds__(256) void prep_all(
    const float* __restrict__ x, const int* __restrict__ mask,
    const float* __restrict__ Wq, const float* __restrict__ Wk, const float* __restrict__ Wv,
    const float* __restrict__ Wo, const float* __restrict__ W1, const float* __restrict__ W2,
    const float* __restrict__ bq, const float* __restrict__ bk, const float* __restrict__ bv,
    bf16* __restrict__ xb, bf16* __restrict__ wqkvT, bf16* __restrict__ WoT,
    bf16* __restrict__ W1T, bf16* __restrict__ W2T, float* __restrict__ bqkv,
    int* __restrict__ newpos, int* __restrict__ Ucnt, float* __restrict__ cvec)
{
    __shared__ __align__(16) char shraw[64 * 65 * 4];
    int bid = blockIdx.x, t = threadIdx.x;
    if (bid < 8192) {
        int idx = bid * 256 + t;
        float4 v = ((const float4*)x)[idx];
        bf16x4 o = { (bf16)v.x, (bf16)v.y, (bf16)v.z, (bf16)v.w };
        ((bf16x4*)xb)[idx] = o;
    } else if (bid < 11264) {
        float (*T)[65] = (float (*)[65])shraw;
        int tb = bid - 8192;
        const float* src; bf16* dst; int srcLd, dstLd, tR, tC; bool scale = false;
        if (tb < 768) {                        // Wq/Wk/Wv per-head [1024x64] -> [64x1024]
            int mat = tb >> 4, ty = tb & 15;
            int h = mat & 15, type = mat >> 4;
            const float* W = (type == 0) ? Wq : (type == 1 ? Wk : Wv);
            src = W + (size_t)h * ND * NDK;
            srcLd = NDK; tR = ty * 64; tC = 0;
            dst = wqkvT + ((size_t)type * 1024 + h * 64) * ND;
            dstLd = ND;
            scale = (type == 0);
        } else if (tb < 1024) {                // Wo
            int b2 = tb - 768; int ty = b2 >> 4, tx = b2 & 15;
            src = Wo; srcLd = ND; tR = ty * 64; tC = tx * 64; dst = WoT; dstLd = ND;
        } else if (tb < 2048) {                // W1 [1024x4096] -> W1T
            int b2 = tb - 1024; int ty = b2 >> 6, tx = b2 & 63;
            src = W1; srcLd = NDFF; tR = ty * 64; tC = tx * 64; dst = W1T; dstLd = ND;
        } else {                               // W2 [4096x1024] -> W2T
            int b2 = tb - 2048; int ty = b2 >> 4, tx = b2 & 15;
            src = W2; srcLd = ND; tR = ty * 64; tC = tx * 64; dst = W2T; dstLd = NDFF;
        }
        int c0 = t & 63, r0 = t >> 6;
        #pragma unroll
        for (int rr = 0; rr < 16; rr++) {
            int row = rr * 4 + r0;
            T[row][c0] = src[(size_t)(tR + row) * srcLd + tC + c0];
        }
        __syncthreads();
        #pragma unroll
        for (int cc = 0; cc < 16; cc++) {
            int col = cc * 4 + r0;
            float v = T[c0][col];
            if (scale) v *= 0.125f;
            dst[(size_t)(tC + col) * dstLd + tR + c0] = (bf16)v;
        }
    } else if (bid < 11276) {
        int n = (bid - 11264) * 256 + t;
        if (n < 3072) {
            int type = n >> 10, hk = n & 1023;
            const float* bb = (type == 0) ? bq : (type == 1 ? bk : bv);
            float v = bb[hk];
            if (type == 0) v *= 0.125f;
            bqkv[n] = v;
        }
    } else if (bid < 11284) {
        int* sums  = (int*)shraw;
        int* scans = (int*)(shraw + 1024);
        int b = bid - 11276;
        const int* mb = mask + b * NS;
        int m[4], s = 0;
        #pragma unroll
        for (int k = 0; k < 4; k++) { m[k] = (mb[t * 4 + k] != 0) ? 1 : 0; s += m[k]; }
        sums[t] = s;
        __syncthreads();
        if (t == 0) {
            int acc = 0;
            for (int i = 0; i < 256; i++) { scans[i] = acc; acc += sums[i]; }
            scans[256] = acc;
            Ucnt[b] = acc;
        }
        __syncthreads();
        int U = scans[256];
        int p = scans[t];
        #pragma unroll
        for (int k = 0; k < 4; k++) {
            int j = t * 4 + k;
            newpos[b * NS + j] = m[k] ? p : U + (j - p);
            p += m[k];
        }
    } else {
        float4 z = {0.f, 0.f, 0.f, 0.f};
        ((float4*)cvec)[(bid - 11284) * 256 + t] = z;
    }
}

// ---------------------------------------------------------------------------
// Core B (measured 892 TF on g6): 128x256, BK=64, 8 waves, 2 phases x 16
// MFMA, TRIPLE-buf LDS (144 KiB): stage tile t+2 during tile t, counted
// vmcnt(6) (never 0 in steady state).
// ---------------------------------------------------------------------------
__device__ __forceinline__ void gemmB_core(
    const bf16* __restrict__ A, const bf16* __restrict__ BT, int K,
    int rowBase, int colBase, f32x4 (&acc)[4][4], bf16* As, bf16* Bs)
{
    constexpr int ABUF = 128 * 64, BBUF = 256 * 64;
    const int tid = threadIdx.x, lane = tid & 63, wid = tid >> 6;
    const int wm = wid >> 2, wn = wid & 3;
    const int lrow = lane & 15, lq = lane >> 4;
    const int srow = lane >> 3, gblk = (lane & 7) ^ srow;
    const int co0 = (lq ^ (lrow & 7)) * 8;
    const int co1 = ((4 + lq) ^ (lrow & 7)) * 8;
    f32x4 zz = {0.f, 0.f, 0.f, 0.f};
    #pragma unroll
    for (int i = 0; i < 4; i++)
        #pragma unroll
        for (int j = 0; j < 4; j++) acc[i][j] = zz;
    const bf16* Ag = A  + (size_t)(rowBase + wid * 8 + srow) * K + gblk * 8;
    const bf16* Bg = BT + (size_t)(colBase + wid * 8 + srow) * K + gblk * 8;

#define SGA2(kt, bi, rr) GLDS(Ag + (size_t)(kt) * 64 + (size_t)(rr) * 64 * K, \
                              As + (bi) * ABUF + ((rr) * 64 + wid * 8) * 64)
#define SGB2(kt, bi, rr) GLDS(Bg + (size_t)(kt) * 64 + (size_t)(rr) * 64 * K, \
                              Bs + (bi) * BBUF + ((rr) * 64 + wid * 8) * 64)
#define RDA2() do { _Pragma("unroll") for (int i_ = 0; i_ < 4; i_++) { \
    int ro_ = (wm * 64 + i_ * 16 + lrow) * 64; \
    af[i_][0] = *(const bf16x8*)&Ab[ro_ + co0]; \
    af[i_][1] = *(const bf16x8*)&Ab[ro_ + co1]; } } while (0)
#define RDB2(dst, NS_) do { _Pragma("unroll") for (int j_ = 0; j_ < 2; j_++) { \
    int ro_ = (wn * 64 + (NS_) * 32 + j_ * 16 + lrow) * 64; \
    dst[j_][0] = *(const bf16x8*)&Bb[ro_ + co0]; \
    dst[j_][1] = *(const bf16x8*)&Bb[ro_ + co1]; } } while (0)
#define CLUSTER_B(bfx, JO) do { \
    __builtin_amdgcn_s_barrier(); \
    asm volatile("s_waitcnt lgkmcnt(0)" ::: "memory"); \
    __builtin_amdgcn_sched_barrier(0); \
    __builtin_amdgcn_s_setprio(1); \
    _Pragma("unroll") \
    for (int i_ = 0; i_ < 4; i_++) \
        _Pragma("unroll") \
        for (int j_ = 0; j_ < 2; j_++) { \
            acc[i_][(JO) + j_] = mfma16(af[i_][0], bfx[j_][0], acc[i_][(JO) + j_]); \
            acc[i_][(JO) + j_] = mfma16(af[i_][1], bfx[j_][1], acc[i_][(JO) + j_]); \
        } \
    __builtin_amdgcn_s_setprio(0); \
} while (0)

    const int nt = K >> 6;
    SGA2(0, 0, 0); SGA2(0, 0, 1);
    SGB2(0, 0, 0); SGB2(0, 0, 1); SGB2(0, 0, 2); SGB2(0, 0, 3);
    SGA2(1, 1, 0); SGA2(1, 1, 1);
    SGB2(1, 1, 0); SGB2(1, 1, 1); SGB2(1, 1, 2); SGB2(1, 1, 3);
    asm volatile("s_waitcnt vmcnt(6)" ::: "memory");
    __builtin_amdgcn_s_barrier();

    int ci = 0, si = 2;
    for (int t = 0; t < nt; ++t) {
        const bf16* Ab = As + ci * ABUF;
        const bf16* Bb = Bs + ci * BBUF;
        const bool pf = (t + 2 < nt);
        bf16x8 af[4][2], bf0[2][2], bf1[2][2];
        RDA2(); RDB2(bf0, 0);
        if (pf) { SGA2(t + 2, si, 0); SGA2(t + 2, si, 1); SGB2(t + 2, si, 0); SGB2(t + 2, si, 1); }
        CLUSTER_B(bf0, 0);
        __builtin_amdgcn_s_barrier();
        RDB2(bf1, 1);
        if (pf) { SGB2(t + 2, si, 2); SGB2(t + 2, si, 3); }
        CLUSTER_B(bf1, 2);
        if (pf)                asm volatile("s_waitcnt vmcnt(6)" ::: "memory");
        else if (t + 1 < nt)   asm volatile("s_waitcnt vmcnt(0)" ::: "memory");
        __builtin_amdgcn_s_barrier();
        ci = (ci == 2) ? 0 : ci + 1;
        si = (si == 2) ? 0 : si + 1;
    }
#undef SGA2
#undef SGB2
#undef RDA2
#undef RDB2
#undef CLUSTER_B
}

// ---------------------------------------------------------------------------
// 8-phase 256x256 core (measured best for g5).
// ---------------------------------------------------------------------------
__device__ __forceinline__ void gemm8p(
    const bf16* __restrict__ A, const bf16* __restrict__ BT, int K,
    int rowBase, int colBase, f32x4 (&acc)[8][4], bf16* As, bf16* Bs)
{
    constexpr int SETSZ = 256 * 64;
    const int tid = threadIdx.x, lane = tid & 63, wid = tid >> 6;
    const int wm = wid >> 2, wn = wid & 3;
    const int lrow = lane & 15, lq = lane >> 4;
    const int s8 = lane >> 3, gblk = (lane & 7) ^ s8;
    const int co0 = (lq ^ (lrow & 7)) * 8;
    const int co1 = ((4 + lq) ^ (lrow & 7)) * 8;
    f32x4 zz = {0.f, 0.f, 0.f, 0.f};
    #pragma unroll
    for (int i = 0; i < 8; i++)
        #pragma unroll
        for (int j = 0; j < 4; j++) acc[i][j] = zz;
    const bf16* Ag = A  + (size_t)(rowBase + wid * 8 + s8) * K + gblk * 8;
    const bf16* Bg = BT + (size_t)(colBase + wid * 8 + s8) * K + gblk * 8;

#define SG_A(kt, set, h) do { \
    GLDS(Ag + (size_t)((h) * 128) * K + (kt) * 64, \
         As + (set) * SETSZ + ((h) * 128 + wid * 8) * 64); \
    GLDS(Ag + (size_t)((h) * 128 + 64) * K + (kt) * 64, \
         As + (set) * SETSZ + ((h) * 128 + 64 + wid * 8) * 64); \
} while (0)
#define SG_B(kt, set, h) do { \
    GLDS(Bg + (size_t)((h) * 128) * K + (kt) * 64, \
         Bs + (set) * SETSZ + ((h) * 128 + wid * 8) * 64); \
    GLDS(Bg + (size_t)((h) * 128 + 64) * K + (kt) * 64, \
         Bs + (set) * SETSZ + ((h) * 128 + 64 + wid * 8) * 64); \
} while (0)
#define RD_A(dst, base, ms) do { _Pragma("unroll") for (int i_ = 0; i_ < 4; i_++) { \
    int ro_ = (wm * 128 + (ms) * 64 + i_ * 16 + lrow) * 64; \
    dst[i_][0] = *(const bf16x8*)&(base)[ro_ + co0]; \
    dst[i_][1] = *(const bf16x8*)&(base)[ro_ + co1]; } } while (0)
#define RD_B(dst, base, ns) do { _Pragma("unroll") for (int j_ = 0; j_ < 2; j_++) { \
    int ro_ = (wn * 64 + (ns) * 32 + j_ * 16 + lrow) * 64; \
    dst[j_][0] = *(const bf16x8*)&(base)[ro_ + co0]; \
    dst[j_][1] = *(const bf16x8*)&(base)[ro_ + co1]; } } while (0)
#define CL8(av, bv, ms, ns) do { \
    __builtin_amdgcn_s_setprio(1); \
    _Pragma("unroll") for (int i_ = 0; i_ < 4; i_++) \
    _Pragma("unroll") for (int j_ = 0; j_ < 2; j_++) { \
        acc[(ms) * 4 + i_][(ns) * 2 + j_] = \
            mfma16(av[i_][0], bv[j_][0], acc[(ms) * 4 + i_][(ns) * 2 + j_]); \
        acc[(ms) * 4 + i_][(ns) * 2 + j_] = \
            mfma16(av[i_][1], bv[j_][1], acc[(ms) * 4 + i_][(ns) * 2 + j_]); } \
    __builtin_amdgcn_s_setprio(0); \
} while (0)
#define BAR8 __builtin_amdgcn_s_barrier()
#define VM4 asm volatile("s_waitcnt vmcnt(4)" ::: "memory")
#define VM0 asm volatile("s_waitcnt vmcnt(0)" ::: "memory")

    const int nt = K >> 6, nIter = nt >> 1;
    SG_B(0, 0, 0); SG_B(0, 0, 1);
    SG_A(0, 0, 0); SG_A(0, 0, 1);
    SG_B(1, 1, 0); SG_B(1, 1, 1);
    VM4; BAR8;
    const bf16* A0b = As;           const bf16* B0b = Bs;
    const bf16* A1b = As + SETSZ;   const bf16* B1b = Bs + SETSZ;
    for (int J = 0; J < nIter; ++J) {
        const int v = 2 * J + 1;
        const bool pf = (J + 1 < nIter);
        bf16x8 a0[4][2], a1[4][2], b0[2][2], b1[2][2];
        RD_A(a0, A0b, 0); RD_B(b0, B0b, 0);
        SG_A(v, 1, 0);
        BAR8; CL8(a0, b0, 0, 0); BAR8;
        RD_B(b1, B0b, 1);
        SG_A(v, 1, 1);
        BAR8; CL8(a0, b1, 0, 1); BAR8;
        RD_A(a1, A0b, 1);
        if (pf) SG_B(v + 1, 0, 0);
        BAR8; CL8(a1, b1, 1, 1); BAR8;
        if (pf) SG_B(v + 1, 0, 1);
        BAR8; CL8(a1, b0, 1, 0);
        if (pf) { VM4; } else { VM0; }
        BAR8;
        RD_A(a0, A1b, 0); RD_B(b0, B1b, 0);
        if (pf) SG_A(v + 1, 0, 0);
        BAR8; CL8(a0, b0, 0, 0); BAR8;
        RD_B(b1, B1b, 1);
        if (pf) SG_A(v + 1, 0, 1);
        BAR8; CL8(a0, b1, 0, 1); BAR8;
        RD_A(a1, A1b, 1);
        if (pf) SG_B(v + 2, 1, 0);
        BAR8; CL8(a1, b1, 1, 1); BAR8;
        if (pf) SG_B(v + 2, 1, 1);
        BAR8; CL8(a1, b0, 1, 0);
        if (pf) { VM4; } else { VM0; }
        BAR8;
    }
#undef SG_A
#undef SG_B
#undef RD_A
#undef RD_B
#undef CL8
#undef BAR8
#undef VM4
#undef VM0
}

// G1: xb @ [Wq|Wk|Wv] + bias; Q row-major, K/V rows through newpos (compacted).
// Core B (128x256), grid 768 (64 bm x 12 bn), XCD-swizzled.
__global__ __launch_bounds__(512, 2) void g1_qkv(
    const bf16* __restrict__ x, const bf16* __restrict__ wqkvT, const float* __restrict__ bqkv,
    const int* __restrict__ newpos,
    bf16* __restrict__ Q, bf16* __restrict__ Kb, bf16* __restrict__ Vb)
{
    __shared__ bf16 As[3 * 128 * 64], Bs[3 * 256 * 64];   // 144 KiB
    f32x4 acc[4][4];
    int g = blockIdx.x;
    int sw = (g & 7) * 96 + (g >> 3);
    int bm = sw / 12, bn = sw % 12;
    int rowBase = bm * 128, colBase = bn * 256;
    gemmB_core(x, wqkvT, ND, rowBase, colBase, acc, As, Bs);
    const int tid = threadIdx.x, lane = tid & 63, wid = tid >> 6;
    const int wm = wid >> 2, wn = wid & 3, lrow = lane & 15, lq = lane >> 4;
    const int type = colBase >> 10;
    int spv[4][4];
    if (type != 0) {
        #pragma unroll
        for (int i = 0; i < 4; i++)
            #pragma unroll
            for (int r = 0; r < 4; r++) {
                int grow = rowBase + wm * 64 + i * 16 + lq * 4 + r;
                spv[i][r] = newpos[grow];
            }
    }
    #pragma unroll
    for (int j = 0; j < 4; j++) {
        int gcol = colBase + wn * 64 + j * 16 + lrow;
        float bias = bqkv[gcol];
        int h = (gcol >> 6) & 15, kk = gcol & 63;
        bf16* dst = (type == 0) ? Q : (type == 1 ? Kb : Vb);
        #pragma unroll
        for (int i = 0; i < 4; i++) {
            #pragma unroll
            for (int r = 0; r < 4; r++) {
                int grow = rowBase + wm * 64 + i * 16 + lq * 4 + r;
                int b = grow >> 10;
                int s = (type == 0) ? (grow & 1023) : spv[i][r];
                dst[((size_t)(b * NH + h) * NS + s) * NDK + kk] = (bf16)(acc[i][j][r] + bias);
            }
        }
    }
}

// G2V: merged g2_stats (blockIdx.x < 8) + vt_trans-with-cvec (x in [8,24)).
// Both depend only on g1's outputs; block-uniform branch; LDS aliased.
__global__ __launch_bounds__(256) void g2v(
    const bf16* __restrict__ Q, const bf16* __restrict__ Kb, const bf16* __restrict__ Vb,
    const int* __restrict__ Ucnt, float2* __restrict__ alpha,
    bf16* __restrict__ Vt, float* __restrict__ cvec)
{
    __shared__ __align__(16) char sraw[128 * 64 * 2];   // 16 KB
    int bh = blockIdx.y, b = bh >> 4;
    const int tid = threadIdx.x;
    if (blockIdx.x >= 8) {
        bf16* T = (bf16*)sraw;                            // 64*72*2 = 9216 B
        float (*red)[64] = (float (*)[64])(sraw + 64 * 72 * 2);
        int s0 = (blockIdx.x - 8) * 64;
        const bf16* src = Vb + ((size_t)bh * NS + s0) * NDK;
        #pragma unroll
        for (int it = 0; it < 2; it++) {
            int g = tid + it * 256;
            int row = g >> 3, c = (g & 7) * 8;
            *(bf16x8*)&T[row * 72 + c] = *(const bf16x8*)&src[row * NDK + c];
        }
        __syncthreads();
        #pragma unroll
        for (int it = 0; it < 2; it++) {
            int g = tid + it * 256;
            int kk = g >> 3, sc = (g & 7) * 8;
            bf16x8 v;
            #pragma unroll
            for (int t = 0; t < 8; t++) v[t] = T[(sc + t) * 72 + kk];
            *(bf16x8*)&Vt[((size_t)bh * NDK + kk) * NS + s0 + sc] = v;
        }
        int U = Ucnt[b];
        int lo = U - s0;
        if (lo < 0) lo = 0;
        if (lo < 64) {                         // block-uniform
            int kk = tid & 63, ss = tid >> 6;
            float a = 0.f;
            for (int r = lo + ss; r < 64; r += 4) a += (float)T[r * 72 + kk];
            red[ss][kk] = a;
            __syncthreads();
            if (ss == 0)
                atomicAdd(&cvec[bh * 64 + kk], red[0][kk] + red[1][kk] + red[2][kk] + red[3][kk]);
        }
        return;
    }
    bf16* Qs = (bf16*)sraw;                               // 128*64*2 = 16 KB
    int jBase = blockIdx.x * 128;
    int U = Ucnt[b];
    if (jBase >= U) {
        if (tid < 128) {
            float2 z; z.x = 0.f; z.y = 0.f;
            alpha[(size_t)bh * NS + jBase + tid] = z;
        }
        return;
    }
    const bf16* Kp = Kb + (size_t)bh * NS * NDK;
    const bf16* Qp = Q + (size_t)bh * NS * NDK;
    const int lane = tid & 63, wid = tid >> 6;
    const int lrow = lane & 15, lq = lane >> 4;
    bf16x8 kf[2][2];
    #pragma unroll
    for (int jt = 0; jt < 2; jt++)
        #pragma unroll
        for (int kh = 0; kh < 2; kh++)
            kf[jt][kh] = *(const bf16x8*)&Kp[(size_t)(jBase + wid * 32 + jt * 16 + lrow) * NDK + kh * 32 + lq * 8];
    const int srow = lane >> 3;
    const int gblk = (lane & 7) ^ srow;
    float Lacc[2][4];
    #pragma unroll
    for (int jt = 0; jt < 2; jt++)
        #pragma unroll
        for (int r = 0; r < 4; r++) Lacc[jt][r] = 0.f;
    f32x4 zz = {0.f, 0.f, 0.f, 0.f};
    for (int i0 = 0; i0 < NS; i0 += 128) {
        __syncthreads();
        #pragma unroll
        for (int it = 0; it < 4; it++)
            GLDS(Qp + (size_t)(i0 + wid * 32 + it * 8 + srow) * NDK + gblk * 8,
                 Qs + (wid * 32 + it * 8) * 64);
        __syncthreads();
        #pragma unroll
        for (int it = 0; it < 8; it++) {
            bf16x8 qb[2];
            #pragma unroll
            for (int kh = 0; kh < 2; kh++)
                qb[kh] = *(const bf16x8*)&Qs[(it * 16 + lrow) * 64 + ((kh * 4 + lq) ^ (lrow & 7)) * 8];
            #pragma unroll
            for (int jt = 0; jt < 2; jt++) {
                f32x4 s = mfma16(kf[jt][0], qb[0], zz);
                s = mfma16(kf[jt][1], qb[1], s);
                #pragma unroll
                for (int r = 0; r < 4; r++) Lacc[jt][r] += __expf(s[r]);
            }
        }
    }
    #pragma unroll
    for (int jt = 0; jt < 2; jt++) {
        #pragma unroll
        for (int r = 0; r < 4; r++) {
            float v = Lacc[jt][r];
            v += __shfl_xor(v, 1); v += __shfl_xor(v, 2);
            v += __shfl_xor(v, 4); v += __shfl_xor(v, 8);
            if (lrow == 0) {
                int j = jBase + wid * 32 + jt * 16 + lq * 4 + r;
                float2 ac;
                ac.x = (j < U) ? 1.f / v : 0.f;
                ac.y = 0.f;
                alpha[(size_t)bh * NS + j] = ac;
            }
        }
    }
}

// G3: ctx[i][kk] = sum_{compacted j < Ur} a_j*exp(s_ij) * v[j][kk] + cvec/1024
__global__ __launch_bounds__(256) void g3_ctx(
    const bf16* __restrict__ Q, const bf16* __restrict__ Kb, const bf16* __restrict__ Vt,
    const float2* __restrict__ alpha, const int* __restrict__ Ucnt,
    const float* __restrict__ cvec, bf16* __restrict__ ctx)
{
    __shared__ bf16 Ks[64 * 64];
    __shared__ bf16 Vs[64 * 64];
    __shared__ bf16 Ps[4 * 64 * 64];
    int bh = blockIdx.y, iBase = blockIdx.x * 256;
    int b = bh >> 4, h = bh & 15;
    int U = Ucnt[b];
    int Ur = (U + 63) & ~63;
    const bf16* Qp = Q + (size_t)bh * NS * NDK;
    const bf16* Kp = Kb + (size_t)bh * NS * NDK;
    const bf16* Vp = Vt + (size_t)bh * NDK * NS;
    const float2* al = alpha + (size_t)bh * NS;
    const int tid = threadIdx.x, lane = tid & 63, wid = tid >> 6;
    const int lrow = lane & 15, lq = lane >> 4;
    const int iw = iBase + wid * 64;
    bf16x8 qf[4][2];
    #pragma unroll
    for (int it = 0; it < 4; it++)
        #pragma unroll
        for (int kh = 0; kh < 2; kh++)
            qf[it][kh] = *(const bf16x8*)&Qp[(size_t)(iw + it * 16 + lrow) * NDK + kh * 32 + lq * 8];
    const int srow = lane >> 3;
    const int gblk = (lane & 7) ^ srow;
    f32x4 cacc[4][4];
    f32x4 zz = {0.f, 0.f, 0.f, 0.f};
    #pragma unroll
    for (int it = 0; it < 4; it++)
        #pragma unroll
        for (int kt = 0; kt < 4; kt++) cacc[it][kt] = zz;
    bf16* Pw = Ps + wid * 64 * 64;
    for (int j0 = 0; j0 < Ur; j0 += 64) {
        __syncthreads();
        #pragma unroll
        for (int it = 0; it < 2; it++)
            GLDS(Kp + (size_t)(j0 + wid * 16 + it * 8 + srow) * NDK + gblk * 8,
                 Ks + (wid * 16 + it * 8) * 64);
        #pragma unroll
        for (int it = 0; it < 2; it++)
            GLDS(Vp + (size_t)(wid * 16 + it * 8 + srow) * NS + j0 + gblk * 8,
                 Vs + (wid * 16 + it * 8) * 64);
        __syncthreads();
        bf16x8 kb[4][2];
        #pragma unroll
        for (int jt = 0; jt < 4; jt++)
            #pragma unroll
            for (int kh = 0; kh < 2; kh++)
                kb[jt][kh] = *(const bf16x8*)&Ks[(jt * 16 + lrow) * 64 + ((kh * 4 + lq) ^ (lrow & 7)) * 8];
        #pragma unroll
        for (int jt = 0; jt < 4; jt++) {
            float2 acj[4];
            #pragma unroll
            for (int r = 0; r < 4; r++) acj[r] = al[j0 + jt * 16 + lq * 4 + r];
            #pragma unroll
            for (int it = 0; it < 4; it++) {
                f32x4 s = mfma16(kb[jt][0], qf[it][0], zz);
                s = mfma16(kb[jt][1], qf[it][1], s);
                bf16x4 pv;
                #pragma unroll
                for (int r = 0; r < 4; r++)
                    pv[r] = (bf16)(acj[r].x * __expf(s[r]) + acj[r].y);
                int i = it * 16 + lrow;
                int jb = jt * 2 + (lq >> 1);
                *(bf16x4*)&Pw[i * 64 + ((jb ^ (i & 7)) * 8) + (lq & 1) * 4] = pv;
            }
        }
        bf16x8 vb[4][2];
        #pragma unroll
        for (int kt = 0; kt < 4; kt++)
            #pragma unroll
            for (int kh = 0; kh < 2; kh++)
                vb[kt][kh] = *(const bf16x8*)&Vs[(kt * 16 + lrow) * 64 + ((kh * 4 + lq) ^ (lrow & 7)) * 8];
        #pragma unroll
        for (int it = 0; it < 4; it++) {
            bf16x8 pa[2];
            #pragma unroll
            for (int kh = 0; kh < 2; kh++)
                pa[kh] = *(const bf16x8*)&Pw[(it * 16 + lrow) * 64 + ((kh * 4 + lq) ^ (lrow & 7)) * 8];
            #pragma unroll
            for (int kt = 0; kt < 4; kt++) {
                cacc[it][kt] = mfma16(pa[0], vb[kt][0], cacc[it][kt]);
                cacc[it][kt] = mfma16(pa[1], vb[kt][1], cacc[it][kt]);
            }
        }
    }
    #pragma unroll
    for (int kt = 0; kt < 4; kt++) {
        int col = h * NDK + kt * 16 + lrow;
        float cv = cvec[bh * 64 + kt * 16 + lrow] * (1.f / 1024.f);
        #pragma unroll
        for (int it = 0; it < 4; it++) {
            #pragma unroll
            for (int r = 0; r < 4; r++) {
                int i = iw + it * 16 + lq * 4 + r;
                ctx[(size_t)(b * NS + i) * ND + col] = (bf16)(cacc[it][kt][r] + cv);
            }
        }
    }
}

// G4: t1b = bf16(ctx @ Wo + bo + xb)   core B, grid 256 (64 bm x 4 bn).
// (GEMM+epilogue validated in R9; rendezvous/LN fusion removed -- it cost
//  ~110us/use via device-scope RMW-poll congestion.)
__global__ __launch_bounds__(512, 2) void g4_proj(
    const bf16* __restrict__ ctx, const bf16* __restrict__ WoT, const float* __restrict__ bo,
    const bf16* __restrict__ xb, bf16* __restrict__ t1b)
{
    __shared__ bf16 As[3 * 128 * 64], Bs[3 * 256 * 64];   // 144 KiB
    f32x4 acc[4][4];
    int g = blockIdx.x;
    int sw = (g & 7) * 32 + (g >> 3);
    int bm = sw >> 2, bn = sw & 3;
    int rowBase = bm * 128, colBase = bn * 256;
    gemmB_core(ctx, WoT, ND, rowBase, colBase, acc, As, Bs);
    const int tid = threadIdx.x, lane = tid & 63, wid = tid >> 6;
    const int wm = wid >> 2, wn = wid & 3, lrow = lane & 15, lq = lane >> 4;
    #pragma unroll
    for (int j = 0; j < 4; j++) {
        int gcol = colBase + wn * 64 + j * 16 + lrow;
        float bias = bo[gcol];
        #pragma unroll
        for (int i = 0; i < 4; i++) {
            #pragma unroll
            for (int r = 0; r < 4; r++) {
                int grow = rowBase + wm * 64 + i * 16 + lq * 4 + r;
                float v = acc[i][j][r] + bias + (float)xb[(size_t)grow * ND + gcol];
                t1b[(size_t)grow * ND + gcol] = (bf16)v;
            }
        }
    }
}

// G5: hb = relu(yb @ W1 + b1)   8-phase core, grid 512 (32x16)
__global__ __launch_bounds__(512, 2) void g5_ffn1(
    const bf16* __restrict__ y, const bf16* __restrict__ W1T, const float* __restrict__ b1,
    bf16* __restrict__ hb)
{
    __shared__ bf16 As[2 * 256 * 64], Bs[2 * 256 * 64];   // 128 KiB
    f32x4 acc[8][4];
    int g = blockIdx.x;
    int sw = (g & 7) * 64 + (g >> 3);
    int bm = sw >> 4, bn = sw & 15;
    int rowBase = bm * 256, colBase = bn * 256;
    gemm8p(y, W1T, ND, rowBase, colBase, acc, As, Bs);
    const int tid = threadIdx.x, lane = tid & 63, wid = tid >> 6;
    const int wm = wid >> 2, wn = wid & 3, lrow = lane & 15, lq = lane >> 4;
    #pragma unroll
    for (int j = 0; j < 4; j++) {
        int gcol = colBase + wn * 64 + j * 16 + lrow;
        float bias = b1[gcol];
        #pragma unroll
        for (int i = 0; i < 8; i++) {
            #pragma unroll
            for (int r = 0; r < 4; r++) {
                int grow = rowBase + wm * 128 + i * 16 + lq * 4 + r;
                float v = fmaxf(acc[i][j][r] + bias, 0.f);
                hb[(size_t)grow * NDFF + gcol] = (bf16)v;
            }
        }
    }
}

// G6: zb = bf16(hb @ W2 + b2 + yb)   core B, grid 256, K=4096
__global__ __launch_bounds__(512, 2) void g6_ffn2(
    const bf16* __restrict__ hb, const bf16* __restrict__ W2T, const float* __restrict__ b2,
    const bf16* __restrict__ yb, bf16* __restrict__ zb)
{
    __shared__ bf16 As[3 * 128 * 64], Bs[3 * 256 * 64];   // 144 KiB
    f32x4 acc[4][4];
    int g = blockIdx.x;
    int sw = (g & 7) * 32 + (g >> 3);
    int bm = sw >> 2, bn = sw & 3;
    int rowBase = bm * 128, colBase = bn * 256;
    gemmB_core(hb, W2T, NDFF, rowBase, colBase, acc, As, Bs);
    const int tid = threadIdx.x, lane = tid & 63, wid = tid >> 6;
    const int wm = wid >> 2, wn = wid & 3, lrow = lane & 15, lq = lane >> 4;
    #pragma unroll
    for (int j = 0; j < 4; j++) {
        int gcol = colBase + wn * 64 + j * 16 + lrow;
        float bias = b2[gcol];
        #pragma unroll
        for (int i = 0; i < 4; i++) {
            #pragma unroll
            for (int r = 0; r < 4; r++) {
                int grow = rowBase + wm * 64 + i * 16 + lq * 4 + r;
                float v = acc[i][j][r] + bias + (float)yb[(size_t)grow * ND + gcol];
                zb[(size_t)grow * ND + gcol] = (bf16)v;
            }
        }
    }
}

// Row LayerNorm over D=1024, bf16 in; writes bf16 (outb) and/or fp32 (outf)
__global__ __launch_bounds__(256) void ln_kernel(
    const bf16* __restrict__ in, bf16* __restrict__ outb, float* __restrict__ outf,
    const float* __restrict__ g, const float* __restrict__ bb)
{
    int row = blockIdx.x, tid = threadIdx.x;
    const bf16* p = in + (size_t)row * ND;
    bf16x4 v4 = *(const bf16x4*)&p[tid * 4];
    float vv[4] = {(float)v4[0], (float)v4[1], (float)v4[2], (float)v4[3]};
    float s = vv[0] + vv[1] + vv[2] + vv[3];
    float q = vv[0]*vv[0] + vv[1]*vv[1] + vv[2]*vv[2] + vv[3]*vv[3];
    #pragma unroll
    for (int m = 1; m < 64; m <<= 1) { s += __shfl_xor(s, m); q += __shfl_xor(q, m); }
    __shared__ float rs[4], rq[4];
    int wid = tid >> 6, lane = tid & 63;
    if (lane == 0) { rs[wid] = s; rq[wid] = q; }
    __syncthreads();
    s = rs[0] + rs[1] + rs[2] + rs[3];
    q = rq[0] + rq[1] + rq[2] + rq[3];
    float mean = s * (1.f / 1024.f);
    float var = q * (1.f / 1024.f) - mean * mean;
    float rstd = 1.f / sqrtf(var + 1e-5f);
    float4 of;
    bf16x4 ob;
    #pragma unroll
    for (int k = 0; k < 4; k++) {
        int col = tid * 4 + k;
        float yv = (vv[k] - mean) * rstd * g[col] + bb[col];
        ((float*)&of)[k] = yv;
        ob[k] = (bf16)yv;
    }
    if (outb) *(bf16x4*)&outb[(size_t)row * ND + tid * 4] = ob;
    if (outf) ((float4*)(outf + (size_t)row * ND))[tid] = of;
}

// ---------------------------------------------------------------------------
extern "C" void kernel_launch(void* const* d_in, const int* in_sizes, int n_in,
                              void* d_out, int out_size, void* d_ws, size_t ws_size,
                              hipStream_t stream)
{
    const float* x    = (const float*)d_in[0];
    const int*   mask = (const int*)d_in[1];
    const float* Wq   = (const float*)d_in[2];
    const float* bq   = (const float*)d_in[3];
    const float* Wk   = (const float*)d_in[4];
    const float* bk   = (const float*)d_in[5];
    const float* Wv   = (const float*)d_in[6];
    const float* bv   = (const float*)d_in[7];
    const float* Wo   = (const float*)d_in[8];
    const float* bo   = (const float*)d_in[9];
    const float* ga   = (const float*)d_in[10];
    const float* ba   = (const float*)d_in[11];
    const float* W1   = (const float*)d_in[12];
    const float* b1   = (const float*)d_in[13];
    const float* W2   = (const float*)d_in[14];
    const float* b2   = (const float*)d_in[15];
    const float* gf   = (const float*)d_in[16];
    const float* bfb  = (const float*)d_in[17];

    size_t off = 0;
    auto alloc = [&](size_t n) { char* p = (char*)d_ws + off; off += (n + 255) & ~(size_t)255; return (void*)p; };
    bf16*   wqkvT = (bf16*)  alloc((size_t)3072 * 1024 * 2);           // 6 MB
    bf16*   WoT   = (bf16*)  alloc((size_t)1024 * 1024 * 2);           // 2 MB
    bf16*   W1T   = (bf16*)  alloc((size_t)4096 * 1024 * 2);           // 8 MB
    bf16*   W2T   = (bf16*)  alloc((size_t)1024 * 4096 * 2);           // 8 MB
    float*  bqkv  = (float*) alloc(3072 * 4);
    float2* alpha = (float2*)alloc((size_t)NB * NH * NS * 8);          // 1 MB
    int*    newpos= (int*)   alloc((size_t)NB * NS * 4);               // 32 KB
    int*    Ucnt  = (int*)   alloc(NB * 4);
    float*  cvec  = (float*) alloc((size_t)NB * NH * NDK * 4);         // 32 KB
    bf16*   xb    = (bf16*)  alloc((size_t)8192 * 1024 * 2);           // 16 MB
    // 64 MB union: Qb|Kb|Vt|ctx live until g4; hb (g5/g6) aliases the whole block
    bf16*   ub    = (bf16*)  alloc((size_t)8192 * 4096 * 2);           // 64 MB
    bf16*   Qb    = ub;
    bf16*   Kb    = ub + (size_t)8192 * 1024;
    bf16*   Vt    = ub + (size_t)2 * 8192 * 1024;
    bf16*   ctx   = ub + (size_t)3 * 8192 * 1024;
    bf16*   hb    = ub;
    // 16 MB region shared by Vb (g1->g2v), t1b (g4->ln1), zb (g6->ln2)
    bf16*   t1b   = (bf16*)  alloc((size_t)8192 * 1024 * 2);           // 16 MB
    bf16*   Vb    = t1b;
    bf16*   zb    = t1b;
    bf16*   yb    = (bf16*)  alloc((size_t)8192 * 1024 * 2);           // 16 MB

    // 9 launches: round-8 structure (best measured) + g2v merge + g4 on coreB.
    prep_all<<<11292, 256, 0, stream>>>(x, mask, Wq, Wk, Wv, Wo, W1, W2, bq, bk, bv,
                                        xb, wqkvT, WoT, W1T, W2T, bqkv, newpos, Ucnt, cvec);
    g1_qkv<<<768, 512, 0, stream>>>(xb, wqkvT, bqkv, newpos, Qb, Kb, Vb);
    g2v<<<dim3(24, 128), 256, 0, stream>>>(Qb, Kb, Vb, Ucnt, alpha, Vt, cvec);
    g3_ctx<<<dim3(4, 128), 256, 0, stream>>>(Qb, Kb, Vt, alpha, Ucnt, cvec, ctx);
    g4_proj<<<256, 512, 0, stream>>>(ctx, WoT, bo, xb, t1b);
    ln_kernel<<<8192, 256, 0, stream>>>(t1b, yb, nullptr, ga, ba);
    g5_ffn1<<<512, 512, 0, stream>>>(yb, W1T, b1, hb);
    g6_ffn2<<<256, 512, 0, stream>>>(hb, W2T, b2, yb, zb);
    ln_kernel<<<8192, 256, 0, stream>>>(zb, nullptr, (float*)d_out, gf, bfb);
}